// Round 5
// baseline (78.144 us; speedup 1.0000x reference)
//
#include <hip/hip_runtime.h>

#define INF   256   // input features
#define OUTF  128   // NUM_HEADS * HEAD_DIM

typedef __attribute__((ext_vector_type(8))) short bf16x8;
typedef __attribute__((ext_vector_type(4))) float f32x4;

__device__ __forceinline__ ushort f2bf(float f) {
    unsigned u = __float_as_uint(f);
    u += 0x7FFFu + ((u >> 16) & 1u);   // round-to-nearest-even
    return (ushort)(u >> 16);
}

// ---------------------------------------------------------------------------
__global__ __launch_bounds__(256) void wbf_kernel(const float* __restrict__ W,
                                                  ushort* __restrict__ Wbf) {
    int t = blockIdx.x * 256 + threadIdx.x;
    if (t < OUTF * INF) Wbf[t] = f2bf(W[t]);
}

// flags[dst] = 1 (racy identical stores: benign). flags 100 KB -> L2.
__global__ __launch_bounds__(256) void mark_kernel(const int* __restrict__ dst,
                                                   unsigned char* __restrict__ flags,
                                                   int E) {
    int e = blockIdx.x * 256 + threadIdx.x;
    if (e < E) flags[dst[e]] = 1;
}

// ---------------------------------------------------------------------------
// out = flag ? elu(x @ W^T) : 0, bf16 MFMA. Barrier-free, LDS-free.
// Occupancy fix vs R4: wave tile = 32 rows x 64 cols (acc 32 VGPR), block of
// 4 waves covers 64 rows x 128 cols -> 1563 blocks = 6252 waves = 24.4/CU
// (2x R4). Col-half waves of the same rows are adjacent -> x re-read is
// L2/L3-hit. Fragment scheme (verified in R3/R4): A row=lane&15,
// k=(lane>>4)*8+j; B col=lane&15 same k; D col=lane&15, row=(lane>>4)*4+j.
__global__ __launch_bounds__(256) void gemm_fused(const float* __restrict__ x,
        const ushort* __restrict__ Wbf, const unsigned char* __restrict__ flags,
        float* __restrict__ out, int nrows) {
    const int t    = threadIdx.x;
    const int lane = t & 63;
    const int w    = t >> 6;
    const int row0 = blockIdx.x * 64 + (w >> 1) * 32;
    const int col0 = (w & 1) * 64;
    if (row0 >= nrows) return;
    const bool full = (row0 + 32 <= nrows);

    const int rlo = lane & 15;     // row-in-tile (A) / col-in-tile (B,D)
    const int kg  = lane >> 4;     // k-group: 8 contiguous k each

    f32x4 acc[2][4];
#pragma unroll
    for (int rt = 0; rt < 2; ++rt)
#pragma unroll
        for (int ct = 0; ct < 4; ++ct)
            acc[rt][ct] = (f32x4){0.f, 0.f, 0.f, 0.f};

#pragma unroll
    for (int ks = 0; ks < 8; ++ks) {
        // A fragments: 2 row-tiles, 8 fp32 each from x, convert to bf16
        bf16x8 af[2];
#pragma unroll
        for (int rt = 0; rt < 2; ++rt) {
            int r = row0 + rt * 16 + rlo;
            if (!full && r >= nrows) r = nrows - 1;   // harmless clamp
            const float* px = x + (size_t)r * INF + ks * 32 + kg * 8;
            float4 v0 = *reinterpret_cast<const float4*>(px);
            float4 v1 = *reinterpret_cast<const float4*>(px + 4);
            union { ushort s[8]; bf16x8 v; } ua;
            ua.s[0] = f2bf(v0.x); ua.s[1] = f2bf(v0.y);
            ua.s[2] = f2bf(v0.z); ua.s[3] = f2bf(v0.w);
            ua.s[4] = f2bf(v1.x); ua.s[5] = f2bf(v1.y);
            ua.s[6] = f2bf(v1.z); ua.s[7] = f2bf(v1.w);
            af[rt] = ua.v;
        }
        // B fragments (4 col-tiles) from L1/L2-resident Wbf + MFMAs
#pragma unroll
        for (int ct = 0; ct < 4; ++ct) {
            uint4 raw = *reinterpret_cast<const uint4*>(
                Wbf + (size_t)(col0 + ct * 16 + rlo) * INF + ks * 32 + kg * 8);
            bf16x8 bf = __builtin_bit_cast(bf16x8, raw);
            acc[0][ct] = __builtin_amdgcn_mfma_f32_16x16x32_bf16(af[0], bf, acc[0][ct], 0, 0, 0);
            acc[1][ct] = __builtin_amdgcn_mfma_f32_16x16x32_bf16(af[1], bf, acc[1][ct], 0, 0, 0);
        }
    }

    // Epilogue: D col = lane&15, row = kg*4 + j; flag-gated elu
#pragma unroll
    for (int rt = 0; rt < 2; ++rt) {
#pragma unroll
        for (int j = 0; j < 4; ++j) {
            int r = row0 + rt * 16 + kg * 4 + j;
            if (!full && r >= nrows) continue;
            const bool fl = flags[r] != 0;
            float* orow = out + (size_t)r * OUTF + col0 + rlo;
#pragma unroll
            for (int ct = 0; ct < 4; ++ct) {
                float v = acc[rt][ct][j];
                float o = 0.f;
                if (fl) o = v > 0.f ? v : (__expf(v) - 1.f);
                orow[ct * 16] = o;
            }
        }
    }
}

// ---------------------------------------------------------------------------
extern "C" void kernel_launch(void* const* d_in, const int* in_sizes, int n_in,
                              void* d_out, int out_size, void* d_ws, size_t ws_size,
                              hipStream_t stream) {
    const float* x  = (const float*)d_in[0];
    const int*   ei = (const int*)d_in[1];
    const float* W  = (const float*)d_in[3];
    float* out = (float*)d_out;

    const int n = in_sizes[0] / INF;   // 100000 nodes
    const int E = in_sizes[1] / 2;     // 1600000 edges

    ushort* Wbf          = (ushort*)d_ws;                         // 65536 B
    unsigned char* flags = (unsigned char*)((char*)d_ws + 65536); // n bytes

    hipMemsetAsync(flags, 0, (size_t)n, stream);
    wbf_kernel<<<(OUTF * INF + 255) / 256, 256, 0, stream>>>(W, Wbf);
    mark_kernel<<<(E + 255) / 256, 256, 0, stream>>>(ei + E, flags, E);

    const int nblocks = (n + 63) / 64;   // 1563 blocks x 4 waves = 6252 waves
    gemm_fused<<<nblocks, 256, 0, stream>>>(x, Wbf, flags, out, n);
}

// Round 6
// 61.393 us; speedup vs baseline: 1.2729x; 1.2729x over previous
//
#include <hip/hip_runtime.h>

#define INF   256   // input features
#define OUTF  128   // NUM_HEADS * HEAD_DIM
#define BM    128   // rows per block

typedef __attribute__((ext_vector_type(8))) short bf16x8;
typedef __attribute__((ext_vector_type(4))) float f32x4;

__device__ __forceinline__ ushort f2bf(float f) {
    unsigned u = __float_as_uint(f);
    u += 0x7FFFu + ((u >> 16) & 1u);   // round-to-nearest-even
    return (ushort)(u >> 16);
}

// ---------------------------------------------------------------------------
// Reorder W ([OUTF][INF] fp32) into MFMA B-fragment order, bf16:
// frag(ct,ks) = 64 lanes x 16B contiguous; lane -> col=ct*16+(lane&15),
// k=ks*32+(lane>>4)*8 .. +7.  Wf byte offset = ((ct*8+ks)*64+lane)*16.
__global__ __launch_bounds__(256) void wfrag_kernel(const float* __restrict__ W,
                                                    ushort* __restrict__ Wf) {
    int t = blockIdx.x * 256 + threadIdx.x;   // 8192 threads total
    int lane = t & 63;
    int frag = t >> 6;
    int ct = frag >> 3, ks = frag & 7;
    int c = ct * 16 + (lane & 15);
    int k = ks * 32 + (lane >> 4) * 8;
    const float* p = W + (size_t)c * INF + k;
    float4 v0 = *reinterpret_cast<const float4*>(p);
    float4 v1 = *reinterpret_cast<const float4*>(p + 4);
    ushort* q = Wf + (size_t)t * 8;
    q[0] = f2bf(v0.x); q[1] = f2bf(v0.y); q[2] = f2bf(v0.z); q[3] = f2bf(v0.w);
    q[4] = f2bf(v1.x); q[5] = f2bf(v1.y); q[6] = f2bf(v1.z); q[7] = f2bf(v1.w);
}

// flags[dst] = 1 (racy identical stores: benign). flags 100 KB -> L2.
__global__ __launch_bounds__(256) void mark_kernel(const int* __restrict__ dst,
                                                   unsigned char* __restrict__ flags,
                                                   int E) {
    int e = blockIdx.x * 256 + threadIdx.x;
    if (e < E) flags[dst[e]] = 1;
}

// ---------------------------------------------------------------------------
// out = flag ? elu(x @ W^T) : 0, bf16 MFMA.
// TA-friendly structure: every global load instruction is contiguous.
//  - stage: whole 128-row x 256-k strip -> 64KB LDS bf16; each wave-instr
//    reads exactly one 1KB row of x; XOR-swizzle ((r&7)<<4) on 16B slots.
//  - ONE __syncthreads, then barrier-free compute: ds_read_b128 A-frags +
//    coalesced 1KB B-frag loads from pre-reordered Wf + 128 MFMAs/wave.
__global__ __launch_bounds__(256) void gemm_fused(const float* __restrict__ x,
        const ushort* __restrict__ Wf, const unsigned char* __restrict__ flags,
        float* __restrict__ out, int nrows) {
    __shared__ ushort As[BM * 256];   // 64 KB, swizzled bf16 strip

    const int t    = threadIdx.x;
    const int lane = t & 63;
    const int w    = t >> 6;
    const int row0 = blockIdx.x * BM;

    // ---- stage: 32 iters, each wave-instr = one contiguous 1KB x-row ----
#pragma unroll
    for (int i = 0; i < 32; ++i) {
        int f  = i * 256 + t;        // float4 index in strip
        int r  = f >> 6;             // 0..127  (= i*4 + w within a wave)
        int c4 = f & 63;             // 0..63   (= lane within a wave)
        int gr = row0 + r;
        if (gr >= nrows) gr = nrows - 1;   // clamp: contiguous & harmless
        float4 v = *reinterpret_cast<const float4*>(x + (size_t)gr * INF + c4 * 4);
        ushort4 b4 = make_ushort4(f2bf(v.x), f2bf(v.y), f2bf(v.z), f2bf(v.w));
        int byte = (r * 512 + c4 * 8) ^ ((r & 7) << 4);
        *reinterpret_cast<ushort4*>(reinterpret_cast<char*>(As) + byte) = b4;
    }
    __syncthreads();   // the only barrier

    // ---- compute: wave owns rows w*32..+31, all 128 cols ----
    const int wr0 = w * 32;
    const int rlo = lane & 15;
    const int kg  = lane >> 4;

    f32x4 acc[2][8];
#pragma unroll
    for (int rt = 0; rt < 2; ++rt)
#pragma unroll
        for (int ct = 0; ct < 8; ++ct)
            acc[rt][ct] = (f32x4){0.f, 0.f, 0.f, 0.f};

#pragma unroll
    for (int ks = 0; ks < 8; ++ks) {
        bf16x8 af[2];
#pragma unroll
        for (int rt = 0; rt < 2; ++rt) {
            int lr = wr0 + rt * 16 + rlo;
            int byte = (lr * 512 + ks * 64 + kg * 16) ^ ((lr & 7) << 4);
            af[rt] = *reinterpret_cast<const bf16x8*>(
                         reinterpret_cast<const char*>(As) + byte);
        }
#pragma unroll
        for (int ct = 0; ct < 8; ++ct) {
            // contiguous 1KB per wave-instr (fragment-ordered Wf)
            bf16x8 bf = *reinterpret_cast<const bf16x8*>(
                Wf + ((size_t)(ct * 8 + ks) * 64 + lane) * 8);
            acc[0][ct] = __builtin_amdgcn_mfma_f32_16x16x32_bf16(af[0], bf, acc[0][ct], 0, 0, 0);
            acc[1][ct] = __builtin_amdgcn_mfma_f32_16x16x32_bf16(af[1], bf, acc[1][ct], 0, 0, 0);
        }
    }

    // ---- epilogue: D col = lane&15, row = kg*4+j; flag-gated elu ----
#pragma unroll
    for (int rt = 0; rt < 2; ++rt) {
#pragma unroll
        for (int j = 0; j < 4; ++j) {
            int r = row0 + wr0 + rt * 16 + kg * 4 + j;
            if (r >= nrows) continue;
            const bool fl = flags[r] != 0;
            float* orow = out + (size_t)r * OUTF + rlo;
#pragma unroll
            for (int ct = 0; ct < 8; ++ct) {
                float v = acc[rt][ct][j];
                float o = 0.f;
                if (fl) o = v > 0.f ? v : (__expf(v) - 1.f);
                orow[ct * 16] = o;
            }
        }
    }
}

// ---------------------------------------------------------------------------
extern "C" void kernel_launch(void* const* d_in, const int* in_sizes, int n_in,
                              void* d_out, int out_size, void* d_ws, size_t ws_size,
                              hipStream_t stream) {
    const float* x  = (const float*)d_in[0];
    const int*   ei = (const int*)d_in[1];
    const float* W  = (const float*)d_in[3];
    float* out = (float*)d_out;

    const int n = in_sizes[0] / INF;   // 100000 nodes
    const int E = in_sizes[1] / 2;     // 1600000 edges

    ushort* Wf           = (ushort*)d_ws;                         // 65536 B
    unsigned char* flags = (unsigned char*)((char*)d_ws + 65536); // n bytes

    hipMemsetAsync(flags, 0, (size_t)n, stream);
    wfrag_kernel<<<32, 256, 0, stream>>>(W, Wf);
    mark_kernel<<<(E + 255) / 256, 256, 0, stream>>>(ei + E, flags, E);

    const int nblocks = (n + BM - 1) / BM;   // 782
    gemm_fused<<<nblocks, 256, 0, stream>>>(x, Wf, flags, out, n);
}

// Round 7
// 54.458 us; speedup vs baseline: 1.4349x; 1.1273x over previous
//
#include <hip/hip_runtime.h>

#define INF   256   // input features
#define OUTF  128   // NUM_HEADS * HEAD_DIM
#define BM    64    // rows per block (32KB LDS -> ~5 blocks/CU residency)

typedef __attribute__((ext_vector_type(8))) short bf16x8;
typedef __attribute__((ext_vector_type(4))) float f32x4;

__device__ __forceinline__ ushort f2bf(float f) {
    unsigned u = __float_as_uint(f);
    u += 0x7FFFu + ((u >> 16) & 1u);   // round-to-nearest-even
    return (ushort)(u >> 16);
}

// ---------------------------------------------------------------------------
// Reorder W ([OUTF][INF] fp32) into MFMA B-fragment order, bf16:
// frag(ct,ks) = 64 lanes x 16B contiguous; lane -> col=ct*16+(lane&15),
// k=ks*32+(lane>>4)*8 .. +7.  Wf byte offset = ((ct*8+ks)*64+lane)*16.
__global__ __launch_bounds__(256) void wfrag_kernel(const float* __restrict__ W,
                                                    ushort* __restrict__ Wf) {
    int t = blockIdx.x * 256 + threadIdx.x;   // 8192 threads total
    int lane = t & 63;
    int frag = t >> 6;
    int ct = frag >> 3, ks = frag & 7;
    int c = ct * 16 + (lane & 15);
    int k = ks * 32 + (lane >> 4) * 8;
    const float* p = W + (size_t)c * INF + k;
    float4 v0 = *reinterpret_cast<const float4*>(p);
    float4 v1 = *reinterpret_cast<const float4*>(p + 4);
    ushort* q = Wf + (size_t)t * 8;
    q[0] = f2bf(v0.x); q[1] = f2bf(v0.y); q[2] = f2bf(v0.z); q[3] = f2bf(v0.w);
    q[4] = f2bf(v1.x); q[5] = f2bf(v1.y); q[6] = f2bf(v1.z); q[7] = f2bf(v1.w);
}

// flags[dst] = 1 (racy identical stores: benign). flags 100 KB -> L2.
__global__ __launch_bounds__(256) void mark_kernel(const int* __restrict__ dst,
                                                   unsigned char* __restrict__ flags,
                                                   int E) {
    int e = blockIdx.x * 256 + threadIdx.x;
    if (e < E) flags[dst[e]] = 1;
}

// ---------------------------------------------------------------------------
// out = flag ? elu(x @ W^T) : 0, bf16 MFMA.
// R7 change vs R6: BM 128 -> 64 (LDS 64KB -> 32KB) so ~5 blocks/CU are
// resident; inter-block TLP overlaps one block's HBM stage with others'
// compute. Still ONE barrier; every global load instruction contiguous.
// Wave tile: 32 rows x 64 cols (2 row-tiles x 4 col-tiles, acc 32 VGPR).
__global__ __launch_bounds__(256) void gemm_fused(const float* __restrict__ x,
        const ushort* __restrict__ Wf, const unsigned char* __restrict__ flags,
        float* __restrict__ out, int nrows) {
    __shared__ ushort As[BM * 256];   // 32 KB, swizzled bf16 strip

    const int t    = threadIdx.x;
    const int lane = t & 63;
    const int w    = t >> 6;
    const int row0 = blockIdx.x * BM;

    // ---- stage: 16 iters, each wave-instr = one contiguous 1KB x-row ----
#pragma unroll
    for (int i = 0; i < 16; ++i) {
        int f  = i * 256 + t;        // float4 index in strip
        int r  = f >> 6;             // 0..63
        int c4 = f & 63;             // 0..63
        int gr = row0 + r;
        if (gr >= nrows) gr = nrows - 1;   // clamp: contiguous & harmless
        float4 v = *reinterpret_cast<const float4*>(x + (size_t)gr * INF + c4 * 4);
        ushort4 b4 = make_ushort4(f2bf(v.x), f2bf(v.y), f2bf(v.z), f2bf(v.w));
        int byte = (r * 512 + c4 * 8) ^ ((r & 7) << 4);
        *reinterpret_cast<ushort4*>(reinterpret_cast<char*>(As) + byte) = b4;
    }
    __syncthreads();   // the only barrier

    // ---- compute: wave owns 32 rows x 64 cols ----
    const int wr0  = (w >> 1) * 32;    // row half within block
    const int col0 = (w & 1) * 64;     // col half
    const int rlo = lane & 15;
    const int kg  = lane >> 4;

    f32x4 acc[2][4];
#pragma unroll
    for (int rt = 0; rt < 2; ++rt)
#pragma unroll
        for (int ct = 0; ct < 4; ++ct)
            acc[rt][ct] = (f32x4){0.f, 0.f, 0.f, 0.f};

#pragma unroll
    for (int ks = 0; ks < 8; ++ks) {
        bf16x8 af[2];
#pragma unroll
        for (int rt = 0; rt < 2; ++rt) {
            int lr = wr0 + rt * 16 + rlo;
            int byte = (lr * 512 + ks * 64 + kg * 16) ^ ((lr & 7) << 4);
            af[rt] = *reinterpret_cast<const bf16x8*>(
                         reinterpret_cast<const char*>(As) + byte);
        }
#pragma unroll
        for (int ct = 0; ct < 4; ++ct) {
            // contiguous 1KB per wave-instr (fragment-ordered Wf, L1/L2-hit)
            int ctg = (col0 >> 4) + ct;
            bf16x8 bf = *reinterpret_cast<const bf16x8*>(
                Wf + ((size_t)(ctg * 8 + ks) * 64 + lane) * 8);
            acc[0][ct] = __builtin_amdgcn_mfma_f32_16x16x32_bf16(af[0], bf, acc[0][ct], 0, 0, 0);
            acc[1][ct] = __builtin_amdgcn_mfma_f32_16x16x32_bf16(af[1], bf, acc[1][ct], 0, 0, 0);
        }
    }

    // ---- epilogue: D col = lane&15, row = kg*4+j; flag-gated elu ----
#pragma unroll
    for (int rt = 0; rt < 2; ++rt) {
#pragma unroll
        for (int j = 0; j < 4; ++j) {
            int r = row0 + wr0 + rt * 16 + kg * 4 + j;
            if (r >= nrows) continue;
            const bool fl = flags[r] != 0;
            float* orow = out + (size_t)r * OUTF + col0 + rlo;
#pragma unroll
            for (int ct = 0; ct < 4; ++ct) {
                float v = acc[rt][ct][j];
                float o = 0.f;
                if (fl) o = v > 0.f ? v : (__expf(v) - 1.f);
                orow[ct * 16] = o;
            }
        }
    }
}

// ---------------------------------------------------------------------------
extern "C" void kernel_launch(void* const* d_in, const int* in_sizes, int n_in,
                              void* d_out, int out_size, void* d_ws, size_t ws_size,
                              hipStream_t stream) {
    const float* x  = (const float*)d_in[0];
    const int*   ei = (const int*)d_in[1];
    const float* W  = (const float*)d_in[3];
    float* out = (float*)d_out;

    const int n = in_sizes[0] / INF;   // 100000 nodes
    const int E = in_sizes[1] / 2;     // 1600000 edges

    ushort* Wf           = (ushort*)d_ws;                         // 65536 B
    unsigned char* flags = (unsigned char*)((char*)d_ws + 65536); // n bytes

    hipMemsetAsync(flags, 0, (size_t)n, stream);
    wfrag_kernel<<<32, 256, 0, stream>>>(W, Wf);
    mark_kernel<<<(E + 255) / 256, 256, 0, stream>>>(ei + E, flags, E);

    const int nblocks = (n + BM - 1) / BM;   // 1563
    gemm_fused<<<nblocks, 256, 0, stream>>>(x, Wf, flags, out, n);
}

// Round 9
// 52.799 us; speedup vs baseline: 1.4800x; 1.0314x over previous
//
#include <hip/hip_runtime.h>

#define INF   256   // input features
#define OUTF  128   // NUM_HEADS * HEAD_DIM
#define BM    32    // rows per block (16KB LDS -> 8 blocks/CU residency)

typedef __attribute__((ext_vector_type(8))) short bf16x8;
typedef __attribute__((ext_vector_type(4))) float f32x4;

__device__ __forceinline__ ushort f2bf(float f) {
    unsigned u = __float_as_uint(f);
    u += 0x7FFFu + ((u >> 16) & 1u);   // round-to-nearest-even
    return (ushort)(u >> 16);
}

// ---------------------------------------------------------------------------
// Merged setup: (a) flags[dst]=1 for every edge (racy identical stores:
// benign; flags pre-zeroed by memset). (b) first 4096 threads reorder W into
// MFMA B-fragment order, bf16. 64 fragments total: frag = ct*8+ks, ct 0..7,
// ks 0..7; each = 64 lanes x 16B contiguous; lane -> col=ct*16+(lane&15),
// k=ks*32+(lane>>4)*8 .. +7.  Wf byte offset = (frag*64+lane)*16.
// R8 BUG FIXED: bound was t<8192 (128 frags) -> ct up to 15, OOB reads of W
// and a 64KB write overflow over `flags`, racing with the flag stores.
__global__ __launch_bounds__(256) void setup_kernel(const int* __restrict__ dst,
        unsigned char* __restrict__ flags, const float* __restrict__ W,
        ushort* __restrict__ Wf, int E) {
    int t = blockIdx.x * 256 + threadIdx.x;
    if (t < E) flags[dst[t]] = 1;
    if (t < 4096) {
        int lane = t & 63;
        int frag = t >> 6;          // 0..63
        int ct = frag >> 3, ks = frag & 7;   // ct 0..7, ks 0..7
        int c = ct * 16 + (lane & 15);       // 0..127
        int k = ks * 32 + (lane >> 4) * 8;   // 0..248
        const float* p = W + (size_t)c * INF + k;
        float4 v0 = *reinterpret_cast<const float4*>(p);
        float4 v1 = *reinterpret_cast<const float4*>(p + 4);
        ushort* q = Wf + (size_t)t * 8;
        q[0] = f2bf(v0.x); q[1] = f2bf(v0.y); q[2] = f2bf(v0.z); q[3] = f2bf(v0.w);
        q[4] = f2bf(v1.x); q[5] = f2bf(v1.y); q[6] = f2bf(v1.z); q[7] = f2bf(v1.w);
    }
}

// ---------------------------------------------------------------------------
// out = flag ? elu(x @ W^T) : 0, bf16 MFMA.
// BM=32 (16KB LDS) -> ~8 resident blocks/CU; the streaming stage of ~half
// the resident blocks overlaps compute of the rest. ONE barrier; every
// global load instruction contiguous.
// Wave tile: all 32 rows x 32 cols (2 row-tiles x 2 col-tiles, acc 16 VGPR).
__global__ __launch_bounds__(256) void gemm_fused(const float* __restrict__ x,
        const ushort* __restrict__ Wf, const unsigned char* __restrict__ flags,
        float* __restrict__ out, int nrows) {
    __shared__ ushort As[BM * 256];   // 16 KB, swizzled bf16 strip

    const int t    = threadIdx.x;
    const int lane = t & 63;
    const int w    = t >> 6;
    const int row0 = blockIdx.x * BM;

    // ---- stage: 8 iters, each wave-instr = one contiguous 1KB x-row ----
#pragma unroll
    for (int i = 0; i < 8; ++i) {
        int f  = i * 256 + t;        // 8-byte-unit index in strip
        int r  = f >> 6;             // 0..31
        int c4 = f & 63;             // 0..63
        int gr = row0 + r;
        if (gr >= nrows) gr = nrows - 1;   // clamp: contiguous & harmless
        float4 v = *reinterpret_cast<const float4*>(x + (size_t)gr * INF + c4 * 4);
        ushort4 b4 = make_ushort4(f2bf(v.x), f2bf(v.y), f2bf(v.z), f2bf(v.w));
        int byte = (r * 512 + c4 * 8) ^ ((r & 7) << 4);
        *reinterpret_cast<ushort4*>(reinterpret_cast<char*>(As) + byte) = b4;
    }
    __syncthreads();   // the only barrier

    // ---- compute: wave owns all 32 rows x its 32-col quarter ----
    const int col0 = w * 32;
    const int rlo  = lane & 15;
    const int kg   = lane >> 4;

    f32x4 acc[2][2];
#pragma unroll
    for (int rt = 0; rt < 2; ++rt)
#pragma unroll
        for (int ct = 0; ct < 2; ++ct)
            acc[rt][ct] = (f32x4){0.f, 0.f, 0.f, 0.f};

#pragma unroll
    for (int ks = 0; ks < 8; ++ks) {
        bf16x8 af[2];
#pragma unroll
        for (int rt = 0; rt < 2; ++rt) {
            int lr = rt * 16 + rlo;
            int byte = (lr * 512 + ks * 64 + kg * 16) ^ ((lr & 7) << 4);
            af[rt] = *reinterpret_cast<const bf16x8*>(
                         reinterpret_cast<const char*>(As) + byte);
        }
#pragma unroll
        for (int ct = 0; ct < 2; ++ct) {
            // contiguous 1KB per wave-instr (fragment-ordered Wf, L1/L2-hit)
            int ctg = (col0 >> 4) + ct;
            bf16x8 bf = *reinterpret_cast<const bf16x8*>(
                Wf + ((size_t)(ctg * 8 + ks) * 64 + lane) * 8);
            acc[0][ct] = __builtin_amdgcn_mfma_f32_16x16x32_bf16(af[0], bf, acc[0][ct], 0, 0, 0);
            acc[1][ct] = __builtin_amdgcn_mfma_f32_16x16x32_bf16(af[1], bf, acc[1][ct], 0, 0, 0);
        }
    }

    // ---- epilogue: D col = lane&15, row = kg*4+j; flag-gated elu ----
#pragma unroll
    for (int rt = 0; rt < 2; ++rt) {
#pragma unroll
        for (int j = 0; j < 4; ++j) {
            int r = row0 + rt * 16 + kg * 4 + j;
            if (r >= nrows) continue;
            const bool fl = flags[r] != 0;
            float* orow = out + (size_t)r * OUTF + col0 + rlo;
#pragma unroll
            for (int ct = 0; ct < 2; ++ct) {
                float v = acc[rt][ct][j];
                float o = 0.f;
                if (fl) o = v > 0.f ? v : (__expf(v) - 1.f);
                orow[ct * 16] = o;
            }
        }
    }
}

// ---------------------------------------------------------------------------
extern "C" void kernel_launch(void* const* d_in, const int* in_sizes, int n_in,
                              void* d_out, int out_size, void* d_ws, size_t ws_size,
                              hipStream_t stream) {
    const float* x  = (const float*)d_in[0];
    const int*   ei = (const int*)d_in[1];
    const float* W  = (const float*)d_in[3];
    float* out = (float*)d_out;

    const int n = in_sizes[0] / INF;   // 100000 nodes
    const int E = in_sizes[1] / 2;     // 1600000 edges

    ushort* Wf           = (ushort*)d_ws;                         // 65536 B
    unsigned char* flags = (unsigned char*)((char*)d_ws + 65536); // n bytes

    hipMemsetAsync(flags, 0, (size_t)n, stream);
    setup_kernel<<<(E + 255) / 256, 256, 0, stream>>>(ei + E, flags, W, Wf, E);

    const int nblocks = (n + BM - 1) / BM;   // 3125
    gemm_fused<<<nblocks, 256, 0, stream>>>(x, Wf, flags, out, n);
}